// Round 8
// baseline (114.084 us; speedup 1.0000x reference)
//
#include <hip/hip_runtime.h>

#define B_ 2
#define N_ 28
#define D_ 128
#define H_ 8
#define DK_ 16
#define R_ (B_ * N_ * N_)   // 1568
#define ROWS_PER_BLK 8      // 196 blocks per projection

// ---------------------------------------------------------------------------
// DIAGNOSTIC ROUND: R1 kernels exactly, but attn_kernel launched 11x
// (idempotent). dur_us = ovh + P + 11*A + G  =>  A = (dur - 33.6)/10.
// ---------------------------------------------------------------------------

// Kernel 1: all four projections  Y_p = X_p @ W_p^T   (R1-exact)
__global__ __launch_bounds__(128) void proj4_kernel(
    const float* __restrict__ key, const float* __restrict__ value,
    const float* __restrict__ Wlk, const float* __restrict__ Wrk,
    const float* __restrict__ Wlv, const float* __restrict__ Wrv,
    float* __restrict__ ws) {
  const int p = blockIdx.y;
  const float* X = (p < 2) ? key : value;
  const float* W = (p == 0) ? Wlk : (p == 1) ? Wrk : (p == 2) ? Wlv : Wrv;
  float* Y = ws + (size_t)p * R_ * D_;

  const int r0 = blockIdx.x * ROWS_PER_BLK;
  const int c = threadIdx.x;

  __shared__ __align__(16) float xs[ROWS_PER_BLK][D_];
#pragma unroll
  for (int i = 0; i < ROWS_PER_BLK; ++i)
    xs[i][c] = X[(size_t)(r0 + i) * D_ + c];
  __syncthreads();

  const float4* w4 = reinterpret_cast<const float4*>(W + (size_t)c * D_);
  float acc[ROWS_PER_BLK];
#pragma unroll
  for (int i = 0; i < ROWS_PER_BLK; ++i) acc[i] = 0.f;

#pragma unroll
  for (int k = 0; k < D_ / 4; ++k) {
    const float4 wv = w4[k];
#pragma unroll
    for (int i = 0; i < ROWS_PER_BLK; ++i) {
      const float4 xv = reinterpret_cast<const float4*>(xs[i])[k];
      acc[i] += xv.x * wv.x + xv.y * wv.y + xv.z * wv.z + xv.w * wv.w;
    }
  }

#pragma unroll
  for (int i = 0; i < ROWS_PER_BLK; ++i)
    Y[(size_t)(r0 + i) * D_ + c] = acc[i];
}

// Kernel 2: attention (R1-exact v1 body)
__global__ __launch_bounds__(128) void attn_kernel(
    const float* __restrict__ ws, const int* __restrict__ mask,
    float* __restrict__ xout) {
  const float* lk = ws;
  const float* rk = ws + (size_t)1 * R_ * D_;
  const float* lv = ws + (size_t)2 * R_ * D_;
  const float* rv = ws + (size_t)3 * R_ * D_;

  const int bxy = blockIdx.x;   // (b*28 + x)*28 + y
  const int y = bxy % N_;
  const int bx = bxy / N_;      // b*28 + x
  const int b = bx / N_;
  const int tid = threadIdx.x;

  const int rowL = bx * N_;          // + a      (rows of lk / lv)
  const int rowR = b * N_ * N_ + y;  // + a*N_   (rows of rk / rv)

  float s[N_];
#pragma unroll
  for (int a = 0; a < N_; ++a) {
    float pr = lk[(size_t)(rowL + a) * D_ + tid] *
               rk[(size_t)(rowR + a * N_) * D_ + tid];
    pr += __shfl_xor(pr, 1);
    pr += __shfl_xor(pr, 2);
    pr += __shfl_xor(pr, 4);
    pr += __shfl_xor(pr, 8);
    s[a] = pr * 0.25f;  // / sqrt(DK) = / 4
  }

  const int* mrow = mask + (size_t)rowL * N_ + y;  // mask[(rowL+a)*28 + y]
#pragma unroll
  for (int a = 0; a < N_; ++a)
    if (mrow[(size_t)a * N_] != 0) s[a] = -1e9f;

  float mx = -3.0e38f;
#pragma unroll
  for (int a = 0; a < N_; ++a) mx = fmaxf(mx, s[a]);
  float den = 0.f;
#pragma unroll
  for (int a = 0; a < N_; ++a) {
    s[a] = __expf(s[a] - mx);
    den += s[a];
  }
  const float inv = 1.0f / den;

  float xv = 0.f;
#pragma unroll
  for (int a = 0; a < N_; ++a) {
    xv += s[a] * lv[(size_t)(rowL + a) * D_ + tid] *
          rv[(size_t)(rowR + a * N_) * D_ + tid];
  }
  xout[(size_t)bxy * D_ + tid] = xv * inv;
}

// Kernel 3: out = x @ Wout^T   (R1-exact)
__global__ __launch_bounds__(128) void gemm_out_kernel(
    const float* __restrict__ X, const float* __restrict__ W,
    float* __restrict__ Y) {
  const int r0 = blockIdx.x * ROWS_PER_BLK;
  const int c = threadIdx.x;

  __shared__ __align__(16) float xs[ROWS_PER_BLK][D_];
#pragma unroll
  for (int i = 0; i < ROWS_PER_BLK; ++i)
    xs[i][c] = X[(size_t)(r0 + i) * D_ + c];
  __syncthreads();

  const float4* w4 = reinterpret_cast<const float4*>(W + (size_t)c * D_);
  float acc[ROWS_PER_BLK];
#pragma unroll
  for (int i = 0; i < ROWS_PER_BLK; ++i) acc[i] = 0.f;

#pragma unroll
  for (int k = 0; k < D_ / 4; ++k) {
    const float4 wv = w4[k];
#pragma unroll
    for (int i = 0; i < ROWS_PER_BLK; ++i) {
      const float4 xv = reinterpret_cast<const float4*>(xs[i])[k];
      acc[i] += xv.x * wv.x + xv.y * wv.y + xv.z * wv.z + xv.w * wv.w;
    }
  }

#pragma unroll
  for (int i = 0; i < ROWS_PER_BLK; ++i)
    Y[(size_t)(r0 + i) * D_ + c] = acc[i];
}

extern "C" void kernel_launch(void* const* d_in, const int* in_sizes, int n_in,
                              void* d_out, int out_size, void* d_ws,
                              size_t ws_size, hipStream_t stream) {
  // 0 query (unused), 1 key, 2 value, 3 mask, 4 Wlk, 5 Wrk, 6 Wlv, 7 Wrv,
  // 8 Wq (unused), 9 Wout
  const float* key = (const float*)d_in[1];
  const float* value = (const float*)d_in[2];
  const int* mask = (const int*)d_in[3];
  const float* Wlk = (const float*)d_in[4];
  const float* Wrk = (const float*)d_in[5];
  const float* Wlv = (const float*)d_in[6];
  const float* Wrv = (const float*)d_in[7];
  const float* Wout = (const float*)d_in[9];
  float* out = (float*)d_out;
  float* ws = (float*)d_ws;
  float* xbuf = ws + (size_t)4 * R_ * D_;  // pre-Wout x, [1568][128]

  proj4_kernel<<<dim3(R_ / ROWS_PER_BLK, 4), 128, 0, stream>>>(
      key, value, Wlk, Wrk, Wlv, Wrv, ws);
  // 11 identical (idempotent) attn launches: dur = base + 10*A
  for (int rep = 0; rep < 11; ++rep) {
    attn_kernel<<<dim3(R_), 128, 0, stream>>>(ws, mask, xbuf);
  }
  gemm_out_kernel<<<dim3(R_ / ROWS_PER_BLK), 128, 0, stream>>>(xbuf, Wout, out);
}

// Round 9
// 35.059 us; speedup vs baseline: 3.2541x; 3.2541x over previous
//
#include <hip/hip_runtime.h>

#define B_ 2
#define N_ 28
#define D_ 128
#define H_ 8
#define DK_ 16
#define R_ (B_ * N_ * N_)   // 1568
#define TR_ 32              // rows per GEMM block
#define NBLK_ (R_ / TR_)    // 49 row-tiles

// ---------------------------------------------------------------------------
// Register-tiled GEMM tile: Y[r0..r0+31][0..127] = X[rows] @ W^T
// 256 threads: rq=tid>>5 (row quad), cq=tid&31 (col base). Thread computes
// rows {4rq+j}, cols {cq+32i} (4x4 in registers).
// W staged per-32-k chunk in LDS, XOR-swizzled (phys_k4 = k4 ^ (c&7)) so the
// strided-column ds_read_b128 spans 8 bank slots (baseline pattern, ~12cyc).
// X tile staged once; x-reads are 2-address broadcasts (free).
// FMA:LDS cycle ratio ~2:1 -> FMA-bound.
// ---------------------------------------------------------------------------
__device__ __forceinline__ void gemm_tile(const float* __restrict__ X,
                                          const float* __restrict__ W,
                                          float* __restrict__ Y, int r0) {
  const int tid = threadIdx.x;
  const int rq = tid >> 5;   // 0..7
  const int cq = tid & 31;   // 0..31
  const int swz = cq & 7;

  __shared__ __align__(16) float4 xs4[TR_][33];  // 32 rows x 128 k (pad row)
  __shared__ __align__(16) float4 wl4[D_][8];    // one 32-k chunk, swizzled

  // ---- stage X tile once: 32 rows x 32 float4, coalesced ----
  const float4* X4 = reinterpret_cast<const float4*>(X);
#pragma unroll
  for (int it = 0; it < 4; ++it) {
    const int idx = it * 256 + tid;
    const int r = idx >> 5, k4f = idx & 31;
    xs4[r][k4f] = X4[(size_t)(r0 + r) * 32 + k4f];
  }

  float acc[4][4];
#pragma unroll
  for (int j = 0; j < 4; ++j)
#pragma unroll
    for (int i = 0; i < 4; ++i) acc[j][i] = 0.f;

  const float4* W4 = reinterpret_cast<const float4*>(W);

  for (int ch = 0; ch < 4; ++ch) {
    if (ch) __syncthreads();  // previous chunk fully consumed
    // ---- stage W chunk (128 rows x 8 float4), coalesced, swizzled ----
#pragma unroll
    for (int it = 0; it < 4; ++it) {
      const int idx = it * 256 + tid;
      const int c = idx >> 3, k4 = idx & 7;
      wl4[c][k4 ^ (c & 7)] = W4[(size_t)c * 32 + ch * 8 + k4];
    }
    __syncthreads();  // also covers xs4 on ch==0

#pragma unroll
    for (int k4 = 0; k4 < 8; ++k4) {
      const int phys = k4 ^ swz;
      float4 wv[4], xv[4];
#pragma unroll
      for (int i = 0; i < 4; ++i) wv[i] = wl4[cq + 32 * i][phys];
#pragma unroll
      for (int j = 0; j < 4; ++j) xv[j] = xs4[4 * rq + j][ch * 8 + k4];
#pragma unroll
      for (int j = 0; j < 4; ++j)
#pragma unroll
        for (int i = 0; i < 4; ++i)
          acc[j][i] += xv[j].x * wv[i].x + xv[j].y * wv[i].y +
                       xv[j].z * wv[i].z + xv[j].w * wv[i].w;
    }
  }

#pragma unroll
  for (int j = 0; j < 4; ++j)
#pragma unroll
    for (int i = 0; i < 4; ++i)
      Y[(size_t)(r0 + 4 * rq + j) * D_ + cq + 32 * i] = acc[j][i];
}

// Kernel 1: four projections via the tiled GEMM. ws: [p][1568][128].
__global__ __launch_bounds__(256) void proj4_rt_kernel(
    const float* __restrict__ key, const float* __restrict__ value,
    const float* __restrict__ Wlk, const float* __restrict__ Wrk,
    const float* __restrict__ Wlv, const float* __restrict__ Wrv,
    float* __restrict__ ws) {
  const int p = blockIdx.y;
  const float* X = (p < 2) ? key : value;
  const float* W = (p == 0) ? Wlk : (p == 1) ? Wrk : (p == 2) ? Wlv : Wrv;
  gemm_tile(X, W, ws + (size_t)p * R_ * D_, blockIdx.x * TR_);
}

// Kernel 3: out = x @ Wout^T via the same tile body.
__global__ __launch_bounds__(256) void gemm_out_rt_kernel(
    const float* __restrict__ X, const float* __restrict__ W,
    float* __restrict__ Y) {
  gemm_tile(X, W, Y, blockIdx.x * TR_);
}

// ---------------------------------------------------------------------------
// Kernel 2: attention (R1-exact proven body).
// ---------------------------------------------------------------------------
__global__ __launch_bounds__(128) void attn_kernel(
    const float* __restrict__ ws, const int* __restrict__ mask,
    float* __restrict__ xout) {
  const float* lk = ws;
  const float* rk = ws + (size_t)1 * R_ * D_;
  const float* lv = ws + (size_t)2 * R_ * D_;
  const float* rv = ws + (size_t)3 * R_ * D_;

  const int bxy = blockIdx.x;   // (b*28 + x)*28 + y
  const int y = bxy % N_;
  const int bx = bxy / N_;      // b*28 + x
  const int b = bx / N_;
  const int tid = threadIdx.x;

  const int rowL = bx * N_;          // + a      (rows of lk / lv)
  const int rowR = b * N_ * N_ + y;  // + a*N_   (rows of rk / rv)

  float s[N_];
#pragma unroll
  for (int a = 0; a < N_; ++a) {
    float pr = lk[(size_t)(rowL + a) * D_ + tid] *
               rk[(size_t)(rowR + a * N_) * D_ + tid];
    pr += __shfl_xor(pr, 1);
    pr += __shfl_xor(pr, 2);
    pr += __shfl_xor(pr, 4);
    pr += __shfl_xor(pr, 8);
    s[a] = pr * 0.25f;  // / sqrt(DK) = / 4
  }

  const int* mrow = mask + (size_t)rowL * N_ + y;  // mask[(rowL+a)*28 + y]
#pragma unroll
  for (int a = 0; a < N_; ++a)
    if (mrow[(size_t)a * N_] != 0) s[a] = -1e9f;

  float mx = -3.0e38f;
#pragma unroll
  for (int a = 0; a < N_; ++a) mx = fmaxf(mx, s[a]);
  float den = 0.f;
#pragma unroll
  for (int a = 0; a < N_; ++a) {
    s[a] = __expf(s[a] - mx);
    den += s[a];
  }
  const float inv = 1.0f / den;

  float xv = 0.f;
#pragma unroll
  for (int a = 0; a < N_; ++a) {
    xv += s[a] * lv[(size_t)(rowL + a) * D_ + tid] *
          rv[(size_t)(rowR + a * N_) * D_ + tid];
  }
  xout[(size_t)bxy * D_ + tid] = xv * inv;
}

extern "C" void kernel_launch(void* const* d_in, const int* in_sizes, int n_in,
                              void* d_out, int out_size, void* d_ws,
                              size_t ws_size, hipStream_t stream) {
  // 0 query (unused), 1 key, 2 value, 3 mask, 4 Wlk, 5 Wrk, 6 Wlv, 7 Wrv,
  // 8 Wq (unused), 9 Wout
  const float* key = (const float*)d_in[1];
  const float* value = (const float*)d_in[2];
  const int* mask = (const int*)d_in[3];
  const float* Wlk = (const float*)d_in[4];
  const float* Wrk = (const float*)d_in[5];
  const float* Wlv = (const float*)d_in[6];
  const float* Wrv = (const float*)d_in[7];
  const float* Wout = (const float*)d_in[9];
  float* out = (float*)d_out;
  float* ws = (float*)d_ws;
  float* xbuf = ws + (size_t)4 * R_ * D_;  // pre-Wout x, [1568][128]

  proj4_rt_kernel<<<dim3(NBLK_, 4), 256, 0, stream>>>(key, value, Wlk, Wrk,
                                                      Wlv, Wrv, ws);
  attn_kernel<<<dim3(R_), 128, 0, stream>>>(ws, mask, xbuf);
  gemm_out_rt_kernel<<<dim3(NBLK_), 256, 0, stream>>>(xbuf, Wout, out);
}